// Round 6
// baseline (739.675 us; speedup 1.0000x reference)
//
#include <hip/hip_runtime.h>
#include <hip/hip_bf16.h>
#include <math.h>

#define SS 2048
#define EE 768
#define HH 12
#define DHH 64
#define FFF 3072
#define LL 4

typedef __hip_bfloat16 bf16;
typedef __attribute__((ext_vector_type(8))) short short8;
typedef __attribute__((ext_vector_type(4))) float f32x4;

__device__ __forceinline__ float b2f(short u) {
  union { unsigned int i; float f; } v;
  v.i = ((unsigned int)(unsigned short)u) << 16;
  return v.f;
}
__device__ __forceinline__ bf16 f2b(float f) { return __float2bfloat16(f); }

__device__ __forceinline__ void async_ld16(const void* g, void* l) {
  __builtin_amdgcn_global_load_lds(
      (const __attribute__((address_space(1))) void*)g,
      (__attribute__((address_space(3))) void*)l, 16, 0, 0);
}

// ---------------------------------------------------------------------------
// Fused LN: v = (readx ? x : 0) + bias + sum(parts) + extra; optional x
// writeback; out = LN(v).
// ---------------------------------------------------------------------------
template <typename OutT>
__global__ __launch_bounds__(256) void ln_fused_kernel(
    float* x, const float* __restrict__ bias, const float* __restrict__ part,
    int nparts, const float* __restrict__ extra,
    const float* __restrict__ g, const float* __restrict__ bta,
    int writeback, int readx, OutT* __restrict__ out) {
  int row = blockIdx.x;
  int tid = threadIdx.x;
  float* xr = x + (size_t)row * EE;
  float v0 = 0.f, v1 = 0.f, v2 = 0.f;
  if (readx) { v0 = xr[tid]; v1 = xr[tid + 256]; v2 = xr[tid + 512]; }
  if (bias) { v0 += bias[tid]; v1 += bias[tid + 256]; v2 += bias[tid + 512]; }
  for (int p = 0; p < nparts; p++) {
    const float* pr = part + (size_t)p * SS * EE + (size_t)row * EE;
    v0 += pr[tid]; v1 += pr[tid + 256]; v2 += pr[tid + 512];
  }
  if (extra) {
    const float* er = extra + (size_t)row * EE;
    v0 += er[tid]; v1 += er[tid + 256]; v2 += er[tid + 512];
  }
  if (writeback) { xr[tid] = v0; xr[tid + 256] = v1; xr[tid + 512] = v2; }
  float s  = v0 + v1 + v2;
  float s2 = v0 * v0 + v1 * v1 + v2 * v2;
  #pragma unroll
  for (int off = 32; off >= 1; off >>= 1) {
    s  += __shfl_down(s,  off);
    s2 += __shfl_down(s2, off);
  }
  __shared__ float red[8];
  __shared__ float mb[2];
  int lane = tid & 63, wid = tid >> 6;
  if (lane == 0) { red[wid] = s; red[4 + wid] = s2; }
  __syncthreads();
  if (tid == 0) {
    float ts  = red[0] + red[1] + red[2] + red[3];
    float ts2 = red[4] + red[5] + red[6] + red[7];
    float mu  = ts * (1.0f / EE);
    float var = ts2 * (1.0f / EE) - mu * mu;
    mb[0] = mu; mb[1] = rsqrtf(var + 1e-5f);
  }
  __syncthreads();
  float mu = mb[0], rs = mb[1];
  OutT* orow = out + (size_t)row * EE;
  float o0 = (v0 - mu) * rs * g[tid]       + bta[tid];
  float o1 = (v1 - mu) * rs * g[tid + 256] + bta[tid + 256];
  float o2 = (v2 - mu) * rs * g[tid + 512] + bta[tid + 512];
  if constexpr (sizeof(OutT) == 4) {
    orow[tid] = o0; orow[tid + 256] = o1; orow[tid + 512] = o2;
  } else {
    orow[tid] = f2b(o0); orow[tid + 256] = f2b(o1); orow[tid + 512] = f2b(o2);
  }
}

// ---------------------------------------------------------------------------
// LDS-free mega-transpose: strided reads are lane-coalesced (lane i reads
// src[k][n0+i] -> 256B segment); each thread writes one contiguous 64B chunk
// of the transposed row. Tile: 32 k x 256 n per block.
// Per-layer short offsets: Wqkv_t@0, Wo_t@1769472, W1_t@2359296,
// W2_t@4718592; layer stride 7077888.
// ---------------------------------------------------------------------------
__global__ __launch_bounds__(256) void transpose_all_kernel(
    const float* __restrict__ Wq, const float* __restrict__ Wk,
    const float* __restrict__ Wv, const float* __restrict__ Wo,
    const float* __restrict__ W1, const float* __restrict__ W2,
    bf16* __restrict__ WtAll) {
  int bid = blockIdx.x;
  int l = bid / 864, r = bid % 864;
  bf16* base = WtAll + (size_t)l * 7077888;
  const float* src; bf16* dst; int K, N, rr;
  if (r < 216) {
    int m = r / 72; rr = r % 72;
    src = (m == 0 ? Wq : m == 1 ? Wk : Wv) + (size_t)l * EE * EE;
    dst = base + (size_t)m * 589824; K = 768; N = 768;
  } else if (r < 288) {
    rr = r - 216; src = Wo + (size_t)l * EE * EE; dst = base + 1769472; K = 768; N = 768;
  } else if (r < 576) {
    rr = r - 288; src = W1 + (size_t)l * EE * FFF; dst = base + 2359296; K = 768; N = 3072;
  } else {
    rr = r - 576; src = W2 + (size_t)l * FFF * EE; dst = base + 4718592; K = 3072; N = 768;
  }
  int ntn = N >> 8;                      // N/256 n-tiles
  int k0 = (rr / ntn) * 32, n0 = (rr % ntn) * 256;
  int n = n0 + threadIdx.x;
  float v[32];
  #pragma unroll
  for (int j = 0; j < 32; j++) v[j] = src[(size_t)(k0 + j) * N + n];
  __align__(16) bf16 tmp[32];
  #pragma unroll
  for (int j = 0; j < 32; j++) tmp[j] = f2b(v[j]);
  short* d = (short*)dst + (size_t)n * K + k0;
  *(short8*)(d)      = *(short8*)&tmp[0];
  *(short8*)(d + 8)  = *(short8*)&tmp[8];
  *(short8*)(d + 16) = *(short8*)&tmp[16];
  *(short8*)(d + 24) = *(short8*)&tmp[24];
}

// all 4 layers' q,k,v biases -> bqkv_all[l][2304]. grid 36.
__global__ __launch_bounds__(256) void concat_bias_all_kernel(
    const float* __restrict__ bq, const float* __restrict__ bk,
    const float* __restrict__ bv, float* __restrict__ out) {
  int g = blockIdx.x * 256 + threadIdx.x;
  int l = g / 2304, i = g % 2304;
  out[g] = (i < 768) ? bq[l * 768 + i]
         : (i < 1536 ? bk[l * 768 + i - 768] : bv[l * 768 + i - 1536]);
}

// ---------------------------------------------------------------------------
// bf16 MFMA GEMM: C = A[M,K](lda) @ Bt[N,K]^T + bias. 128x128 tile, BK=64,
// XOR-swizzled k-chunks. Modes:
//  0: ->bf16 (ld N)   1: GELU->bf16 (ld N)
//  4: QKV: n<768 -> Cv bf16 ld 768; n>=768 -> transposed short4 into
//     Cv2 = kvT[(n-768)][2048]
// ---------------------------------------------------------------------------
__global__ __launch_bounds__(256) void gemm_bf16_kernel(
    const bf16* __restrict__ A, int lda, const bf16* __restrict__ Bt,
    const float* __restrict__ bias, void* __restrict__ Cv, void* __restrict__ Cv2,
    int K, int N, int mode) {
  __shared__ __align__(16) short As[128 * 64];
  __shared__ __align__(16) short Bs[128 * 64];
  const int t = threadIdx.x;
  const int wave = t >> 6, lane = t & 63;
  const int m0 = blockIdx.y * 128, n0 = blockIdx.x * 128;

  const int srow = t >> 3;
  const int sw   = (t & 7) ^ (srow & 7);
  const bf16* Ag = A  + (size_t)(m0 + srow) * lda + sw * 8;
  const bf16* Bg = Bt + (size_t)(n0 + srow) * K + sw * 8;

  const int fr = lane & 15, kq = lane >> 4;
  const int wm = (wave >> 1) * 64, wn = (wave & 1) * 64;
  f32x4 acc[4][4] = {};

  for (int k0 = 0; k0 < K; k0 += 64) {
    #pragma unroll
    for (int c = 0; c < 4; c++) {
      async_ld16(Ag + (size_t)(32 * c) * lda + k0, As + c * 2048 + wave * 512);
      async_ld16(Bg + (size_t)(32 * c) * K + k0, Bs + c * 2048 + wave * 512);
    }
    __syncthreads();
    #pragma unroll
    for (int s = 0; s < 2; s++) {
      short8 a[4], b[4];
      #pragma unroll
      for (int i = 0; i < 4; i++) {
        int r = wm + 16 * i + fr;
        int p = (kq + 4 * s) ^ (r & 7);
        a[i] = *(const short8*)(As + r * 64 + p * 8);
      }
      #pragma unroll
      for (int j = 0; j < 4; j++) {
        int r = wn + 16 * j + fr;
        int p = (kq + 4 * s) ^ (r & 7);
        b[j] = *(const short8*)(Bs + r * 64 + p * 8);
      }
      #pragma unroll
      for (int i = 0; i < 4; i++)
        #pragma unroll
        for (int j = 0; j < 4; j++)
          acc[i][j] = __builtin_amdgcn_mfma_f32_16x16x32_bf16(a[i], b[j], acc[i][j], 0, 0, 0);
    }
    __syncthreads();
  }

  // C/D layout: col = lane&15, row = (lane>>4)*4 + reg
  #pragma unroll
  for (int i = 0; i < 4; i++) {
    #pragma unroll
    for (int j = 0; j < 4; j++) {
      const int r0 = m0 + wm + 16 * i + kq * 4;
      const int c  = n0 + wn + 16 * j + fr;
      const float bv = bias[c];
      if (mode == 4) {
        if (n0 < 768) {
          #pragma unroll
          for (int ri = 0; ri < 4; ri++)
            ((bf16*)Cv)[(size_t)(r0 + ri) * 768 + c] = f2b(acc[i][j][ri] + bv);
        } else {
          __align__(8) bf16 tb[4];
          #pragma unroll
          for (int ri = 0; ri < 4; ri++) tb[ri] = f2b(acc[i][j][ri] + bv);
          *(short4*)((short*)Cv2 + ((size_t)(c - 768) << 11) + r0) = *(short4*)&tb[0];
        }
      } else {
        #pragma unroll
        for (int ri = 0; ri < 4; ri++) {
          float val = acc[i][j][ri] + bv;
          const size_t idx = (size_t)(r0 + ri) * N + c;
          if (mode == 1)
            val = 0.5f * val * (1.0f + erff(val * 0.70710678118654752f));
          ((bf16*)Cv)[idx] = f2b(val);
        }
      }
    }
  }
}

// ---------------------------------------------------------------------------
// Residual GEMM (fp32 out): x[idx] = A @ Bt^T + bias + x[idx].
// 128Mx64N tile, BK=64. N fixed = 768 (O-proj and FF2). grid (12, 16).
// ---------------------------------------------------------------------------
__global__ __launch_bounds__(256) void gemm_resid_kernel(
    const bf16* __restrict__ A, int lda, const bf16* __restrict__ Bt,
    const float* __restrict__ bias, float* __restrict__ x, int K) {
  __shared__ __align__(16) short As[128 * 64];   // 16 KB
  __shared__ __align__(16) short Bs[64 * 64];    // 8 KB
  const int t = threadIdx.x;
  const int wave = t >> 6, lane = t & 63;
  const int m0 = blockIdx.y * 128, n0 = blockIdx.x * 64;

  const int srow = t >> 3;
  const int sw   = (t & 7) ^ (srow & 7);
  const bf16* Ag = A  + (size_t)(m0 + srow) * lda + sw * 8;
  const bf16* Bg = Bt + (size_t)(n0 + srow) * K + sw * 8;

  const int fr = lane & 15, kq = lane >> 4;
  const int wm = wave * 32;
  f32x4 acc[2][4] = {};

  for (int k0 = 0; k0 < K; k0 += 64) {
    #pragma unroll
    for (int c = 0; c < 4; c++)
      async_ld16(Ag + (size_t)(32 * c) * lda + k0, As + c * 2048 + wave * 512);
    #pragma unroll
    for (int c = 0; c < 2; c++)
      async_ld16(Bg + (size_t)(32 * c) * K + k0, Bs + c * 2048 + wave * 512);
    __syncthreads();
    #pragma unroll
    for (int s = 0; s < 2; s++) {
      short8 a[2], b[4];
      #pragma unroll
      for (int i = 0; i < 2; i++) {
        int r = wm + 16 * i + fr;
        int p = (kq + 4 * s) ^ (r & 7);
        a[i] = *(const short8*)(As + r * 64 + p * 8);
      }
      #pragma unroll
      for (int j = 0; j < 4; j++) {
        int r = 16 * j + fr;
        int p = (kq + 4 * s) ^ (r & 7);
        b[j] = *(const short8*)(Bs + r * 64 + p * 8);
      }
      #pragma unroll
      for (int i = 0; i < 2; i++)
        #pragma unroll
        for (int j = 0; j < 4; j++)
          acc[i][j] = __builtin_amdgcn_mfma_f32_16x16x32_bf16(a[i], b[j], acc[i][j], 0, 0, 0);
    }
    __syncthreads();
  }

  #pragma unroll
  for (int i = 0; i < 2; i++) {
    #pragma unroll
    for (int j = 0; j < 4; j++) {
      const int r0 = m0 + wm + 16 * i + kq * 4;
      const int c  = n0 + 16 * j + fr;
      const float bv = bias[c];
      #pragma unroll
      for (int ri = 0; ri < 4; ri++) {
        const size_t idx = (size_t)(r0 + ri) * EE + c;
        x[idx] = acc[i][j][ri] + bv + x[idx];
      }
    }
  }
}

// ---------------------------------------------------------------------------
// Fused attention: M_h = 0.125 * K_h^T V_h (4 waves x 512 s, bf16 LDS
// partials), then Gt[n][h*64+d1] = (M_h @ Wo_h)[d1][n] for a 128-n tile.
// grid (6, 12). LDS 40 KB.
// ---------------------------------------------------------------------------
__global__ __launch_bounds__(256) void attn_fused_kernel(
    const bf16* __restrict__ kvT, const bf16* __restrict__ Wo_t,
    bf16* __restrict__ Gt) {
  __shared__ short pbuf[4][4096];   // per-wave bf16 partials (32 KB)
  __shared__ short Ms[4096];        // M_h bf16 (8 KB)
  const int nt = blockIdx.x, h = blockIdx.y;
  const int lane = threadIdx.x & 63, wave = threadIdx.x >> 6;
  const int fr = lane & 15, kq = lane >> 4;
  const short* kT = (const short*)kvT + (size_t)h * 64 * 2048;
  const short* vT = (const short*)kvT + (size_t)(768 + h * 64) * 2048;

  f32x4 acc[4][4] = {};
  for (int it = 0; it < 8; it++) {
    const int s0 = (it * 4 + wave) * 64;
    #pragma unroll
    for (int s = 0; s < 2; s++) {
      short8 a[4], b[4];
      #pragma unroll
      for (int i = 0; i < 4; i++)
        a[i] = *(const short8*)(kT + (size_t)(16 * i + fr) * 2048 + s0 + s * 32 + kq * 8);
      #pragma unroll
      for (int j = 0; j < 4; j++)
        b[j] = *(const short8*)(vT + (size_t)(16 * j + fr) * 2048 + s0 + s * 32 + kq * 8);
      #pragma unroll
      for (int i = 0; i < 4; i++)
        #pragma unroll
        for (int j = 0; j < 4; j++)
          acc[i][j] = __builtin_amdgcn_mfma_f32_16x16x32_bf16(a[i], b[j], acc[i][j], 0, 0, 0);
    }
  }
  #pragma unroll
  for (int i = 0; i < 4; i++)
    #pragma unroll
    for (int j = 0; j < 4; j++)
      #pragma unroll
      for (int ri = 0; ri < 4; ri++)
        pbuf[wave][(16 * i + kq * 4 + ri) * 64 + 16 * j + fr] =
            (short)__bfloat16_as_ushort(f2b(acc[i][j][ri]));
  __syncthreads();
  {
    int e0 = threadIdx.x * 16;
    #pragma unroll
    for (int e = 0; e < 16; e++) {
      float s = b2f(pbuf[0][e0 + e]) + b2f(pbuf[1][e0 + e]) +
                b2f(pbuf[2][e0 + e]) + b2f(pbuf[3][e0 + e]);
      Ms[e0 + e] = (short)__bfloat16_as_ushort(f2b(s * 0.125f));
    }
  }
  __syncthreads();

  // phase 2: G-tile. wave covers 32 n.
  const int nb = nt * 128 + wave * 32;
  f32x4 g[4][2] = {};
  #pragma unroll
  for (int s = 0; s < 2; s++) {
    short8 a[4], b[2];
    #pragma unroll
    for (int i = 0; i < 4; i++)
      a[i] = *(const short8*)(Ms + (16 * i + fr) * 64 + s * 32 + kq * 8);
    #pragma unroll
    for (int j = 0; j < 2; j++)
      b[j] = *(const short8*)((const short*)Wo_t +
             (size_t)(nb + 16 * j + fr) * 768 + h * 64 + s * 32 + kq * 8);
    #pragma unroll
    for (int i = 0; i < 4; i++)
      #pragma unroll
      for (int j = 0; j < 2; j++)
        g[i][j] = __builtin_amdgcn_mfma_f32_16x16x32_bf16(a[i], b[j], g[i][j], 0, 0, 0);
  }
  #pragma unroll
  for (int i = 0; i < 4; i++)
    #pragma unroll
    for (int j = 0; j < 2; j++) {
      const int c = nb + 16 * j + fr;
      const int d1 = 16 * i + kq * 4;
      __align__(8) bf16 tb[4];
      #pragma unroll
      for (int ri = 0; ri < 4; ri++) tb[ri] = f2b(g[i][j][ri]);
      *(short4*)((short*)Gt + (size_t)c * 768 + h * 64 + d1) = *(short4*)&tb[0];
    }
}

// ---------------------------------------------------------------------------
extern "C" void kernel_launch(void* const* d_in, const int* in_sizes, int n_in,
                              void* d_out, int out_size, void* d_ws, size_t ws_size,
                              hipStream_t stream) {
  const float* emb  = (const float*)d_in[0];
  const float* wpe  = (const float*)d_in[1];
  const float* ln1g = (const float*)d_in[2];
  const float* ln1b = (const float*)d_in[3];
  const float* Wq   = (const float*)d_in[4];
  const float* bq   = (const float*)d_in[5];
  const float* Wk   = (const float*)d_in[6];
  const float* bk   = (const float*)d_in[7];
  const float* Wv   = (const float*)d_in[8];
  const float* bv   = (const float*)d_in[9];
  const float* Wo   = (const float*)d_in[10];
  const float* bo   = (const float*)d_in[11];
  const float* ln2g = (const float*)d_in[12];
  const float* ln2b = (const float*)d_in[13];
  const float* W1   = (const float*)d_in[14];
  const float* b1   = (const float*)d_in[15];
  const float* W2   = (const float*)d_in[16];
  const float* b2   = (const float*)d_in[17];
  const float* lnfg = (const float*)d_in[18];
  const float* lnfb = (const float*)d_in[19];

  // Workspace (~90 MB of 256 MiB)
  char* w = (char*)d_ws;
  bf16*  WtAll = (bf16*)w;   w += (size_t)4 * 7077888 * 2;    // 56.6 MB
  float* bqkvA = (float*)w;  w += (size_t)4 * 2304 * 4;
  float* x     = (float*)w;  w += (size_t)SS * EE * 4;        // 6.3 MB
  bf16*  hb    = (bf16*)w;   w += (size_t)SS * EE * 2;        // 3.1 MB
  bf16*  qkvQ  = (bf16*)w;   w += (size_t)SS * EE * 2;        // 3.1 MB
  bf16*  kvT   = (bf16*)w;   w += (size_t)1536 * 2048 * 2;    // 6.3 MB
  bf16*  Gt    = (bf16*)w;   w += (size_t)EE * EE * 2;        // 1.2 MB
  bf16*  mb2   = (bf16*)w;   w += (size_t)SS * FFF * 2;       // 12.6 MB

  dim3 blk(256);
  transpose_all_kernel<<<3456, blk, 0, stream>>>(Wq, Wk, Wv, Wo, W1, W2, WtAll);
  concat_bias_all_kernel<<<36, blk, 0, stream>>>(bq, bk, bv, bqkvA);

  for (int l = 0; l < LL; l++) {
    bf16* Wl = WtAll + (size_t)l * 7077888;
    bf16* Wqkv_t = Wl;
    bf16* Wo_t   = Wl + 1769472;
    bf16* W1_t   = Wl + 2359296;
    bf16* W2_t   = Wl + 4718592;

    if (l == 0) {
      // x = emb + wpe, LN -> hb
      ln_fused_kernel<bf16><<<SS, blk, 0, stream>>>(
          x, nullptr, emb, 1, wpe, ln1g, ln1b, 1, 0, hb);
    } else {
      ln_fused_kernel<bf16><<<SS, blk, 0, stream>>>(
          x, nullptr, nullptr, 0, nullptr, ln1g + l * EE, ln1b + l * EE, 0, 1, hb);
    }
    // fused QKV GEMM: Q -> qkvQ (ld 768), K/V -> kvT transposed
    gemm_bf16_kernel<<<dim3(18, 16), blk, 0, stream>>>(
        hb, EE, Wqkv_t, bqkvA + l * 2304, qkvQ, kvT, EE, 2304, 4);
    // attention folded through Wo: Gt = (M_h @ Wo_h) stacked
    attn_fused_kernel<<<dim3(6, HH), blk, 0, stream>>>(kvT, Wo_t, Gt);
    // x += Q @ Gt^T + bo
    gemm_resid_kernel<<<dim3(12, 16), blk, 0, stream>>>(
        qkvQ, EE, Gt, bo + l * EE, x, EE);
    ln_fused_kernel<bf16><<<SS, blk, 0, stream>>>(
        x, nullptr, nullptr, 0, nullptr, ln2g + l * EE, ln2b + l * EE, 0, 1, hb);
    // FF1 + GELU
    gemm_bf16_kernel<<<dim3(24, 16), blk, 0, stream>>>(
        hb, EE, W1_t, b1 + l * FFF, mb2, nullptr, EE, FFF, 1);
    // x += mb2 @ W2 + b2
    gemm_resid_kernel<<<dim3(12, 16), blk, 0, stream>>>(
        mb2, FFF, W2_t, b2 + l * EE, x, FFF);
  }
  ln_fused_kernel<float><<<SS, blk, 0, stream>>>(
      x, nullptr, nullptr, 0, nullptr, lnfg, lnfb, 0, 1, (float*)d_out);
}

// Round 7
// 704.514 us; speedup vs baseline: 1.0499x; 1.0499x over previous
//
#include <hip/hip_runtime.h>
#include <hip/hip_bf16.h>
#include <math.h>

#define SS 2048
#define EE 768
#define HH 12
#define DHH 64
#define FFF 3072
#define LL 4

typedef __hip_bfloat16 bf16;
typedef __attribute__((ext_vector_type(8))) short short8;
typedef __attribute__((ext_vector_type(4))) float f32x4;

__device__ __forceinline__ float b2f(short u) {
  union { unsigned int i; float f; } v;
  v.i = ((unsigned int)(unsigned short)u) << 16;
  return v.f;
}
__device__ __forceinline__ bf16 f2b(float f) { return __float2bfloat16(f); }
__device__ __forceinline__ unsigned int f2bu(float f) {
  return (unsigned int)__bfloat16_as_ushort(__float2bfloat16(f));
}

__device__ __forceinline__ void async_ld16(const void* g, void* l) {
  __builtin_amdgcn_global_load_lds(
      (const __attribute__((address_space(1))) void*)g,
      (__attribute__((address_space(3))) void*)l, 16, 0, 0);
}

// ---------------------------------------------------------------------------
// Fused LN: v = (readx ? x : 0) + bias + sum(parts) + extra; optional x
// writeback; out = LN(v).
// ---------------------------------------------------------------------------
template <typename OutT>
__global__ __launch_bounds__(256) void ln_fused_kernel(
    float* x, const float* __restrict__ bias, const float* __restrict__ part,
    int nparts, const float* __restrict__ extra,
    const float* __restrict__ g, const float* __restrict__ bta,
    int writeback, int readx, OutT* __restrict__ out) {
  int row = blockIdx.x;
  int tid = threadIdx.x;
  float* xr = x + (size_t)row * EE;
  float v0 = 0.f, v1 = 0.f, v2 = 0.f;
  if (readx) { v0 = xr[tid]; v1 = xr[tid + 256]; v2 = xr[tid + 512]; }
  if (bias) { v0 += bias[tid]; v1 += bias[tid + 256]; v2 += bias[tid + 512]; }
  for (int p = 0; p < nparts; p++) {
    const float* pr = part + (size_t)p * SS * EE + (size_t)row * EE;
    v0 += pr[tid]; v1 += pr[tid + 256]; v2 += pr[tid + 512];
  }
  if (extra) {
    const float* er = extra + (size_t)row * EE;
    v0 += er[tid]; v1 += er[tid + 256]; v2 += er[tid + 512];
  }
  if (writeback) { xr[tid] = v0; xr[tid + 256] = v1; xr[tid + 512] = v2; }
  float s  = v0 + v1 + v2;
  float s2 = v0 * v0 + v1 * v1 + v2 * v2;
  #pragma unroll
  for (int off = 32; off >= 1; off >>= 1) {
    s  += __shfl_down(s,  off);
    s2 += __shfl_down(s2, off);
  }
  __shared__ float red[8];
  __shared__ float mb[2];
  int lane = tid & 63, wid = tid >> 6;
  if (lane == 0) { red[wid] = s; red[4 + wid] = s2; }
  __syncthreads();
  if (tid == 0) {
    float ts  = red[0] + red[1] + red[2] + red[3];
    float ts2 = red[4] + red[5] + red[6] + red[7];
    float mu  = ts * (1.0f / EE);
    float var = ts2 * (1.0f / EE) - mu * mu;
    mb[0] = mu; mb[1] = rsqrtf(var + 1e-5f);
  }
  __syncthreads();
  float mu = mb[0], rs = mb[1];
  OutT* orow = out + (size_t)row * EE;
  float o0 = (v0 - mu) * rs * g[tid]       + bta[tid];
  float o1 = (v1 - mu) * rs * g[tid + 256] + bta[tid + 256];
  float o2 = (v2 - mu) * rs * g[tid + 512] + bta[tid + 512];
  if constexpr (sizeof(OutT) == 4) {
    orow[tid] = o0; orow[tid + 256] = o1; orow[tid + 512] = o2;
  } else {
    orow[tid] = f2b(o0); orow[tid + 256] = f2b(o1); orow[tid + 512] = f2b(o2);
  }
}

// ---------------------------------------------------------------------------
// Mega-transpose, k-pair-packed: tile 64k x 32n per block. Reads are
// lane-coalesced (128B segments); LDS u32 pack (stride 33, <=2-way = free);
// writes are uint4, 8 lanes/row -> 128B contiguous segments per row.
// Per-layer short offsets: Wqkv_t@0, Wo_t@1769472, W1_t@2359296,
// W2_t@4718592; layer stride 7077888.
// ---------------------------------------------------------------------------
__global__ __launch_bounds__(256) void transpose_all_kernel(
    const float* __restrict__ Wq, const float* __restrict__ Wk,
    const float* __restrict__ Wv, const float* __restrict__ Wo,
    const float* __restrict__ W1, const float* __restrict__ W2,
    bf16* __restrict__ WtAll) {
  __shared__ unsigned int lds[32][33];
  int bid = blockIdx.x;
  int l = bid / 3456, r = bid % 3456;
  bf16* base = WtAll + (size_t)l * 7077888;
  const float* src; bf16* dst; int K, N, rr;
  if (r < 864) {
    int m = r / 288; rr = r % 288;
    src = (m == 0 ? Wq : m == 1 ? Wk : Wv) + (size_t)l * EE * EE;
    dst = base + (size_t)m * 589824; K = 768; N = 768;
  } else if (r < 1152) {
    rr = r - 864; src = Wo + (size_t)l * EE * EE; dst = base + 1769472; K = 768; N = 768;
  } else if (r < 2304) {
    rr = r - 1152; src = W1 + (size_t)l * EE * FFF; dst = base + 2359296; K = 768; N = 3072;
  } else {
    rr = r - 2304; src = W2 + (size_t)l * FFF * EE; dst = base + 4718592; K = 3072; N = 768;
  }
  int ntn = N >> 5;                       // N/32 n-tiles
  int k0 = (rr / ntn) * 64, n0 = (rr % ntn) * 32;
  int tx = threadIdx.x & 31, ty = threadIdx.x >> 5;   // n-lane, k-group
  const float* s = src + (size_t)(k0 + ty * 8) * N + n0 + tx;
  #pragma unroll
  for (int j = 0; j < 4; j++) {
    float v0 = s[(size_t)(2 * j) * N];
    float v1 = s[(size_t)(2 * j + 1) * N];
    lds[tx][ty * 4 + j] = (f2bu(v1) << 16) | f2bu(v0);
  }
  __syncthreads();
  int n = threadIdx.x >> 3, kp4 = (threadIdx.x & 7) * 4;
  uint4 o;
  o.x = lds[n][kp4];     o.y = lds[n][kp4 + 1];
  o.z = lds[n][kp4 + 2]; o.w = lds[n][kp4 + 3];
  unsigned int* d = (unsigned int*)dst + (size_t)(n0 + n) * (K >> 1) + (k0 >> 1) + kp4;
  *(uint4*)d = o;
}

// all 4 layers' q,k,v biases -> bqkv_all[l][2304]. grid 36.
__global__ __launch_bounds__(256) void concat_bias_all_kernel(
    const float* __restrict__ bq, const float* __restrict__ bk,
    const float* __restrict__ bv, float* __restrict__ out) {
  int g = blockIdx.x * 256 + threadIdx.x;
  int l = g / 2304, i = g % 2304;
  out[g] = (i < 768) ? bq[l * 768 + i]
         : (i < 1536 ? bk[l * 768 + i - 768] : bv[l * 768 + i - 1536]);
}

// ---------------------------------------------------------------------------
// bf16 MFMA GEMM, double-buffered K-loop: prefetch tile k+1 is issued right
// after the barrier, then tile k is computed -> load latency hidden behind
// ds_read+MFMA; ONE barrier per iteration. 128x128 tile, BK=64, XOR swizzle.
// Modes: 0: ->bf16 (ld N)  1: GELU->bf16 (ld N)
//        4: QKV: n<768 -> Cv bf16 ld 768; n>=768 -> transposed short4 into
//           Cv2 = kvT[(n-768)][2048]
// ---------------------------------------------------------------------------
__global__ __launch_bounds__(256) void gemm_bf16_kernel(
    const bf16* __restrict__ A, int lda, const bf16* __restrict__ Bt,
    const float* __restrict__ bias, void* __restrict__ Cv, void* __restrict__ Cv2,
    int K, int N, int mode) {
  __shared__ __align__(16) short As[2][128 * 64];   // 32 KB
  __shared__ __align__(16) short Bs[2][128 * 64];   // 32 KB
  const int t = threadIdx.x;
  const int wave = t >> 6, lane = t & 63;
  const int m0 = blockIdx.y * 128, n0 = blockIdx.x * 128;

  const int srow = t >> 3;
  const int sw   = (t & 7) ^ (srow & 7);
  const bf16* Ag = A  + (size_t)(m0 + srow) * lda + sw * 8;
  const bf16* Bg = Bt + (size_t)(n0 + srow) * K + sw * 8;

  const int fr = lane & 15, kq = lane >> 4;
  const int wm = (wave >> 1) * 64, wn = (wave & 1) * 64;
  f32x4 acc[4][4] = {};

  // prologue: prefetch k0 = 0 into buffer 0
  #pragma unroll
  for (int c = 0; c < 4; c++) {
    async_ld16(Ag + (size_t)(32 * c) * lda, As[0] + c * 2048 + wave * 512);
    async_ld16(Bg + (size_t)(32 * c) * K,   Bs[0] + c * 2048 + wave * 512);
  }

  int cur = 0;
  for (int k0 = 0; k0 < K; k0 += 64, cur ^= 1) {
    __syncthreads();   // drains prefetch into buf[cur]; protects buf[cur^1]
    if (k0 + 64 < K) {
      #pragma unroll
      for (int c = 0; c < 4; c++) {
        async_ld16(Ag + (size_t)(32 * c) * lda + k0 + 64, As[cur ^ 1] + c * 2048 + wave * 512);
        async_ld16(Bg + (size_t)(32 * c) * K   + k0 + 64, Bs[cur ^ 1] + c * 2048 + wave * 512);
      }
    }
    #pragma unroll
    for (int s = 0; s < 2; s++) {
      short8 a[4], b[4];
      #pragma unroll
      for (int i = 0; i < 4; i++) {
        int r = wm + 16 * i + fr;
        int p = (kq + 4 * s) ^ (r & 7);
        a[i] = *(const short8*)(As[cur] + r * 64 + p * 8);
      }
      #pragma unroll
      for (int j = 0; j < 4; j++) {
        int r = wn + 16 * j + fr;
        int p = (kq + 4 * s) ^ (r & 7);
        b[j] = *(const short8*)(Bs[cur] + r * 64 + p * 8);
      }
      #pragma unroll
      for (int i = 0; i < 4; i++)
        #pragma unroll
        for (int j = 0; j < 4; j++)
          acc[i][j] = __builtin_amdgcn_mfma_f32_16x16x32_bf16(a[i], b[j], acc[i][j], 0, 0, 0);
    }
  }

  // C/D layout: col = lane&15, row = (lane>>4)*4 + reg
  #pragma unroll
  for (int i = 0; i < 4; i++) {
    #pragma unroll
    for (int j = 0; j < 4; j++) {
      const int r0 = m0 + wm + 16 * i + kq * 4;
      const int c  = n0 + wn + 16 * j + fr;
      const float bv = bias[c];
      if (mode == 4) {
        if (n0 < 768) {
          #pragma unroll
          for (int ri = 0; ri < 4; ri++)
            ((bf16*)Cv)[(size_t)(r0 + ri) * 768 + c] = f2b(acc[i][j][ri] + bv);
        } else {
          __align__(8) bf16 tb[4];
          #pragma unroll
          for (int ri = 0; ri < 4; ri++) tb[ri] = f2b(acc[i][j][ri] + bv);
          *(short4*)((short*)Cv2 + ((size_t)(c - 768) << 11) + r0) = *(short4*)&tb[0];
        }
      } else {
        #pragma unroll
        for (int ri = 0; ri < 4; ri++) {
          float val = acc[i][j][ri] + bv;
          const size_t idx = (size_t)(r0 + ri) * N + c;
          if (mode == 1)
            val = 0.5f * val * (1.0f + erff(val * 0.70710678118654752f));
          ((bf16*)Cv)[idx] = f2b(val);
        }
      }
    }
  }
}

// ---------------------------------------------------------------------------
// Residual GEMM (fp32 out), double-buffered: x[idx] = A @ Bt^T + bias + x.
// 128Mx64N tile, BK=64, N = 768. grid (12, 16).
// ---------------------------------------------------------------------------
__global__ __launch_bounds__(256) void gemm_resid_kernel(
    const bf16* __restrict__ A, int lda, const bf16* __restrict__ Bt,
    const float* __restrict__ bias, float* __restrict__ x, int K) {
  __shared__ __align__(16) short As[2][128 * 64];  // 32 KB
  __shared__ __align__(16) short Bs[2][64 * 64];   // 16 KB
  const int t = threadIdx.x;
  const int wave = t >> 6, lane = t & 63;
  const int m0 = blockIdx.y * 128, n0 = blockIdx.x * 64;

  const int srow = t >> 3;
  const int sw   = (t & 7) ^ (srow & 7);
  const bf16* Ag = A  + (size_t)(m0 + srow) * lda + sw * 8;
  const bf16* Bg = Bt + (size_t)(n0 + srow) * K + sw * 8;

  const int fr = lane & 15, kq = lane >> 4;
  const int wm = wave * 32;
  f32x4 acc[2][4] = {};

  #pragma unroll
  for (int c = 0; c < 4; c++)
    async_ld16(Ag + (size_t)(32 * c) * lda, As[0] + c * 2048 + wave * 512);
  #pragma unroll
  for (int c = 0; c < 2; c++)
    async_ld16(Bg + (size_t)(32 * c) * K, Bs[0] + c * 2048 + wave * 512);

  int cur = 0;
  for (int k0 = 0; k0 < K; k0 += 64, cur ^= 1) {
    __syncthreads();
    if (k0 + 64 < K) {
      #pragma unroll
      for (int c = 0; c < 4; c++)
        async_ld16(Ag + (size_t)(32 * c) * lda + k0 + 64, As[cur ^ 1] + c * 2048 + wave * 512);
      #pragma unroll
      for (int c = 0; c < 2; c++)
        async_ld16(Bg + (size_t)(32 * c) * K + k0 + 64, Bs[cur ^ 1] + c * 2048 + wave * 512);
    }
    #pragma unroll
    for (int s = 0; s < 2; s++) {
      short8 a[2], b[4];
      #pragma unroll
      for (int i = 0; i < 2; i++) {
        int r = wm + 16 * i + fr;
        int p = (kq + 4 * s) ^ (r & 7);
        a[i] = *(const short8*)(As[cur] + r * 64 + p * 8);
      }
      #pragma unroll
      for (int j = 0; j < 4; j++) {
        int r = 16 * j + fr;
        int p = (kq + 4 * s) ^ (r & 7);
        b[j] = *(const short8*)(Bs[cur] + r * 64 + p * 8);
      }
      #pragma unroll
      for (int i = 0; i < 2; i++)
        #pragma unroll
        for (int j = 0; j < 4; j++)
          acc[i][j] = __builtin_amdgcn_mfma_f32_16x16x32_bf16(a[i], b[j], acc[i][j], 0, 0, 0);
    }
  }

  #pragma unroll
  for (int i = 0; i < 2; i++) {
    #pragma unroll
    for (int j = 0; j < 4; j++) {
      const int r0 = m0 + wm + 16 * i + kq * 4;
      const int c  = n0 + 16 * j + fr;
      const float bv = bias[c];
      #pragma unroll
      for (int ri = 0; ri < 4; ri++) {
        const size_t idx = (size_t)(r0 + ri) * EE + c;
        x[idx] = acc[i][j][ri] + bv + x[idx];
      }
    }
  }
}

// ---------------------------------------------------------------------------
// Fused attention: M_h = 0.125 * K_h^T V_h (4 waves x 512 s, bf16 LDS
// partials), then Gt[n][h*64+d1] = (M_h @ Wo_h)[d1][n] for a 128-n tile.
// grid (6, 12). LDS 40 KB.
// ---------------------------------------------------------------------------
__global__ __launch_bounds__(256) void attn_fused_kernel(
    const bf16* __restrict__ kvT, const bf16* __restrict__ Wo_t,
    bf16* __restrict__ Gt) {
  __shared__ short pbuf[4][4096];
  __shared__ short Ms[4096];
  const int nt = blockIdx.x, h = blockIdx.y;
  const int lane = threadIdx.x & 63, wave = threadIdx.x >> 6;
  const int fr = lane & 15, kq = lane >> 4;
  const short* kT = (const short*)kvT + (size_t)h * 64 * 2048;
  const short* vT = (const short*)kvT + (size_t)(768 + h * 64) * 2048;

  f32x4 acc[4][4] = {};
  for (int it = 0; it < 8; it++) {
    const int s0 = (it * 4 + wave) * 64;
    #pragma unroll
    for (int s = 0; s < 2; s++) {
      short8 a[4], b[4];
      #pragma unroll
      for (int i = 0; i < 4; i++)
        a[i] = *(const short8*)(kT + (size_t)(16 * i + fr) * 2048 + s0 + s * 32 + kq * 8);
      #pragma unroll
      for (int j = 0; j < 4; j++)
        b[j] = *(const short8*)(vT + (size_t)(16 * j + fr) * 2048 + s0 + s * 32 + kq * 8);
      #pragma unroll
      for (int i = 0; i < 4; i++)
        #pragma unroll
        for (int j = 0; j < 4; j++)
          acc[i][j] = __builtin_amdgcn_mfma_f32_16x16x32_bf16(a[i], b[j], acc[i][j], 0, 0, 0);
    }
  }
  #pragma unroll
  for (int i = 0; i < 4; i++)
    #pragma unroll
    for (int j = 0; j < 4; j++)
      #pragma unroll
      for (int ri = 0; ri < 4; ri++)
        pbuf[wave][(16 * i + kq * 4 + ri) * 64 + 16 * j + fr] =
            (short)__bfloat16_as_ushort(f2b(acc[i][j][ri]));
  __syncthreads();
  {
    int e0 = threadIdx.x * 16;
    #pragma unroll
    for (int e = 0; e < 16; e++) {
      float s = b2f(pbuf[0][e0 + e]) + b2f(pbuf[1][e0 + e]) +
                b2f(pbuf[2][e0 + e]) + b2f(pbuf[3][e0 + e]);
      Ms[e0 + e] = (short)__bfloat16_as_ushort(f2b(s * 0.125f));
    }
  }
  __syncthreads();

  const int nb = nt * 128 + wave * 32;
  f32x4 g[4][2] = {};
  #pragma unroll
  for (int s = 0; s < 2; s++) {
    short8 a[4], b[2];
    #pragma unroll
    for (int i = 0; i < 4; i++)
      a[i] = *(const short8*)(Ms + (16 * i + fr) * 64 + s * 32 + kq * 8);
    #pragma unroll
    for (int j = 0; j < 2; j++)
      b[j] = *(const short8*)((const short*)Wo_t +
             (size_t)(nb + 16 * j + fr) * 768 + h * 64 + s * 32 + kq * 8);
    #pragma unroll
    for (int i = 0; i < 4; i++)
      #pragma unroll
      for (int j = 0; j < 2; j++)
        g[i][j] = __builtin_amdgcn_mfma_f32_16x16x32_bf16(a[i], b[j], g[i][j], 0, 0, 0);
  }
  #pragma unroll
  for (int i = 0; i < 4; i++)
    #pragma unroll
    for (int j = 0; j < 2; j++) {
      const int c = nb + 16 * j + fr;
      const int d1 = 16 * i + kq * 4;
      __align__(8) bf16 tb[4];
      #pragma unroll
      for (int ri = 0; ri < 4; ri++) tb[ri] = f2b(g[i][j][ri]);
      *(short4*)((short*)Gt + (size_t)c * 768 + h * 64 + d1) = *(short4*)&tb[0];
    }
}

// ---------------------------------------------------------------------------
extern "C" void kernel_launch(void* const* d_in, const int* in_sizes, int n_in,
                              void* d_out, int out_size, void* d_ws, size_t ws_size,
                              hipStream_t stream) {
  const float* emb  = (const float*)d_in[0];
  const float* wpe  = (const float*)d_in[1];
  const float* ln1g = (const float*)d_in[2];
  const float* ln1b = (const float*)d_in[3];
  const float* Wq   = (const float*)d_in[4];
  const float* bq   = (const float*)d_in[5];
  const float* Wk   = (const float*)d_in[6];
  const float* bk   = (const float*)d_in[7];
  const float* Wv   = (const float*)d_in[8];
  const float* bv   = (const float*)d_in[9];
  const float* Wo   = (const float*)d_in[10];
  const float* bo   = (const float*)d_in[11];
  const float* ln2g = (const float*)d_in[12];
  const float* ln2b = (const float*)d_in[13];
  const float* W1   = (const float*)d_in[14];
  const float* b1   = (const float*)d_in[15];
  const float* W2   = (const float*)d_in[16];
  const float* b2   = (const float*)d_in[17];
  const float* lnfg = (const float*)d_in[18];
  const float* lnfb = (const float*)d_in[19];

  // Workspace (~90 MB of 256 MiB)
  char* w = (char*)d_ws;
  bf16*  WtAll = (bf16*)w;   w += (size_t)4 * 7077888 * 2;    // 56.6 MB
  float* bqkvA = (float*)w;  w += (size_t)4 * 2304 * 4;
  float* x     = (float*)w;  w += (size_t)SS * EE * 4;        // 6.3 MB
  bf16*  hb    = (bf16*)w;   w += (size_t)SS * EE * 2;        // 3.1 MB
  bf16*  qkvQ  = (bf16*)w;   w += (size_t)SS * EE * 2;        // 3.1 MB
  bf16*  kvT   = (bf16*)w;   w += (size_t)1536 * 2048 * 2;    // 6.3 MB
  bf16*  Gt    = (bf16*)w;   w += (size_t)EE * EE * 2;        // 1.2 MB
  bf16*  mb2   = (bf16*)w;   w += (size_t)SS * FFF * 2;       // 12.6 MB

  dim3 blk(256);
  transpose_all_kernel<<<13824, blk, 0, stream>>>(Wq, Wk, Wv, Wo, W1, W2, WtAll);
  concat_bias_all_kernel<<<36, blk, 0, stream>>>(bq, bk, bv, bqkvA);

  for (int l = 0; l < LL; l++) {
    bf16* Wl = WtAll + (size_t)l * 7077888;
    bf16* Wqkv_t = Wl;
    bf16* Wo_t   = Wl + 1769472;
    bf16* W1_t   = Wl + 2359296;
    bf16* W2_t   = Wl + 4718592;

    if (l == 0) {
      ln_fused_kernel<bf16><<<SS, blk, 0, stream>>>(
          x, nullptr, emb, 1, wpe, ln1g, ln1b, 1, 0, hb);
    } else {
      ln_fused_kernel<bf16><<<SS, blk, 0, stream>>>(
          x, nullptr, nullptr, 0, nullptr, ln1g + l * EE, ln1b + l * EE, 0, 1, hb);
    }
    // fused QKV GEMM: Q -> qkvQ (ld 768), K/V -> kvT transposed
    gemm_bf16_kernel<<<dim3(18, 16), blk, 0, stream>>>(
        hb, EE, Wqkv_t, bqkvA + l * 2304, qkvQ, kvT, EE, 2304, 4);
    // attention folded through Wo: Gt = (M_h @ Wo_h) stacked
    attn_fused_kernel<<<dim3(6, HH), blk, 0, stream>>>(kvT, Wo_t, Gt);
    // x += Q @ Gt^T + bo
    gemm_resid_kernel<<<dim3(12, 16), blk, 0, stream>>>(
        qkvQ, EE, Gt, bo + l * EE, x, EE);
    ln_fused_kernel<bf16><<<SS, blk, 0, stream>>>(
        x, nullptr, nullptr, 0, nullptr, ln2g + l * EE, ln2b + l * EE, 0, 1, hb);
    // FF1 + GELU
    gemm_bf16_kernel<<<dim3(24, 16), blk, 0, stream>>>(
        hb, EE, W1_t, b1 + l * FFF, mb2, nullptr, EE, FFF, 1);
    // x += mb2 @ W2 + b2
    gemm_resid_kernel<<<dim3(12, 16), blk, 0, stream>>>(
        mb2, FFF, W2_t, b2 + l * EE, x, FFF);
  }
  ln_fused_kernel<float><<<SS, blk, 0, stream>>>(
      x, nullptr, nullptr, 0, nullptr, lnfg, lnfb, 0, 1, (float*)d_out);
}

// Round 8
// 598.783 us; speedup vs baseline: 1.2353x; 1.1766x over previous
//
#include <hip/hip_runtime.h>
#include <hip/hip_bf16.h>
#include <math.h>

#define SS 2048
#define EE 768
#define HH 12
#define DHH 64
#define FFF 3072
#define LL 4

typedef __hip_bfloat16 bf16;
typedef __attribute__((ext_vector_type(8))) short short8;
typedef __attribute__((ext_vector_type(4))) float f32x4;

__device__ __forceinline__ float b2f(short u) {
  union { unsigned int i; float f; } v;
  v.i = ((unsigned int)(unsigned short)u) << 16;
  return v.f;
}
__device__ __forceinline__ bf16 f2b(float f) { return __float2bfloat16(f); }
__device__ __forceinline__ unsigned int f2bu(float f) {
  return (unsigned int)__bfloat16_as_ushort(__float2bfloat16(f));
}

__device__ __forceinline__ void async_ld16(const void* g, void* l) {
  __builtin_amdgcn_global_load_lds(
      (const __attribute__((address_space(1))) void*)g,
      (__attribute__((address_space(3))) void*)l, 16, 0, 0);
}

// ---------------------------------------------------------------------------
// Fused LN: v = (readx ? x : 0) + bias + sum(parts) + extra; optional x
// writeback; out = LN(v).
// ---------------------------------------------------------------------------
template <typename OutT>
__global__ __launch_bounds__(256) void ln_fused_kernel(
    float* x, const float* __restrict__ bias, const float* __restrict__ part,
    int nparts, const float* __restrict__ extra,
    const float* __restrict__ g, const float* __restrict__ bta,
    int writeback, int readx, OutT* __restrict__ out) {
  int row = blockIdx.x;
  int tid = threadIdx.x;
  float* xr = x + (size_t)row * EE;
  float v0 = 0.f, v1 = 0.f, v2 = 0.f;
  if (readx) { v0 = xr[tid]; v1 = xr[tid + 256]; v2 = xr[tid + 512]; }
  if (bias) { v0 += bias[tid]; v1 += bias[tid + 256]; v2 += bias[tid + 512]; }
  for (int p = 0; p < nparts; p++) {
    const float* pr = part + (size_t)p * SS * EE + (size_t)row * EE;
    v0 += pr[tid]; v1 += pr[tid + 256]; v2 += pr[tid + 512];
  }
  if (extra) {
    const float* er = extra + (size_t)row * EE;
    v0 += er[tid]; v1 += er[tid + 256]; v2 += er[tid + 512];
  }
  if (writeback) { xr[tid] = v0; xr[tid + 256] = v1; xr[tid + 512] = v2; }
  float s  = v0 + v1 + v2;
  float s2 = v0 * v0 + v1 * v1 + v2 * v2;
  #pragma unroll
  for (int off = 32; off >= 1; off >>= 1) {
    s  += __shfl_down(s,  off);
    s2 += __shfl_down(s2, off);
  }
  __shared__ float red[8];
  __shared__ float mb[2];
  int lane = tid & 63, wid = tid >> 6;
  if (lane == 0) { red[wid] = s; red[4 + wid] = s2; }
  __syncthreads();
  if (tid == 0) {
    float ts  = red[0] + red[1] + red[2] + red[3];
    float ts2 = red[4] + red[5] + red[6] + red[7];
    float mu  = ts * (1.0f / EE);
    float var = ts2 * (1.0f / EE) - mu * mu;
    mb[0] = mu; mb[1] = rsqrtf(var + 1e-5f);
  }
  __syncthreads();
  float mu = mb[0], rs = mb[1];
  OutT* orow = out + (size_t)row * EE;
  float o0 = (v0 - mu) * rs * g[tid]       + bta[tid];
  float o1 = (v1 - mu) * rs * g[tid + 256] + bta[tid + 256];
  float o2 = (v2 - mu) * rs * g[tid + 512] + bta[tid + 512];
  if constexpr (sizeof(OutT) == 4) {
    orow[tid] = o0; orow[tid + 256] = o1; orow[tid + 512] = o2;
  } else {
    orow[tid] = f2b(o0); orow[tid + 256] = f2b(o1); orow[tid + 512] = f2b(o2);
  }
}

// ---------------------------------------------------------------------------
// Mega-transpose (round-7 version, k-pair-packed LDS, uint4 writes).
// ---------------------------------------------------------------------------
__global__ __launch_bounds__(256) void transpose_all_kernel(
    const float* __restrict__ Wq, const float* __restrict__ Wk,
    const float* __restrict__ Wv, const float* __restrict__ Wo,
    const float* __restrict__ W1, const float* __restrict__ W2,
    bf16* __restrict__ WtAll) {
  __shared__ unsigned int lds[32][33];
  int bid = blockIdx.x;
  int l = bid / 3456, r = bid % 3456;
  bf16* base = WtAll + (size_t)l * 7077888;
  const float* src; bf16* dst; int K, N, rr;
  if (r < 864) {
    int m = r / 288; rr = r % 288;
    src = (m == 0 ? Wq : m == 1 ? Wk : Wv) + (size_t)l * EE * EE;
    dst = base + (size_t)m * 589824; K = 768; N = 768;
  } else if (r < 1152) {
    rr = r - 864; src = Wo + (size_t)l * EE * EE; dst = base + 1769472; K = 768; N = 768;
  } else if (r < 2304) {
    rr = r - 1152; src = W1 + (size_t)l * EE * FFF; dst = base + 2359296; K = 768; N = 3072;
  } else {
    rr = r - 2304; src = W2 + (size_t)l * FFF * EE; dst = base + 4718592; K = 3072; N = 768;
  }
  int ntn = N >> 5;
  int k0 = (rr / ntn) * 64, n0 = (rr % ntn) * 32;
  int tx = threadIdx.x & 31, ty = threadIdx.x >> 5;
  const float* s = src + (size_t)(k0 + ty * 8) * N + n0 + tx;
  #pragma unroll
  for (int j = 0; j < 4; j++) {
    float v0 = s[(size_t)(2 * j) * N];
    float v1 = s[(size_t)(2 * j + 1) * N];
    lds[tx][ty * 4 + j] = (f2bu(v1) << 16) | f2bu(v0);
  }
  __syncthreads();
  int n = threadIdx.x >> 3, kp4 = (threadIdx.x & 7) * 4;
  uint4 o;
  o.x = lds[n][kp4];     o.y = lds[n][kp4 + 1];
  o.z = lds[n][kp4 + 2]; o.w = lds[n][kp4 + 3];
  unsigned int* d = (unsigned int*)dst + (size_t)(n0 + n) * (K >> 1) + (k0 >> 1) + kp4;
  *(uint4*)d = o;
}

// all 4 layers' q,k,v biases -> bqkv_all[l][2304]. grid 36.
__global__ __launch_bounds__(256) void concat_bias_all_kernel(
    const float* __restrict__ bq, const float* __restrict__ bk,
    const float* __restrict__ bv, float* __restrict__ out) {
  int g = blockIdx.x * 256 + threadIdx.x;
  int l = g / 2304, i = g % 2304;
  out[g] = (i < 768) ? bq[l * 768 + i]
         : (i < 1536 ? bk[l * 768 + i - 768] : bv[l * 768 + i - 1536]);
}

// ---------------------------------------------------------------------------
// bf16 MFMA GEMM, 64x64 tile (occupancy-first): 16 KB LDS single-buffer,
// 4 waves x (2x2 MFMA 16x16x32), BK=64, XOR swizzle. grid (N/64, M/64).
// Modes: 1: GELU->bf16 (ld N)
//        4: QKV: n<768 -> Cv bf16 ld 768; n>=768 -> transposed short4 into
//           Cv2 = kvT[(n-768)][2048]
// ---------------------------------------------------------------------------
__global__ __launch_bounds__(256) void gemm_bf16_kernel(
    const bf16* __restrict__ A, int lda, const bf16* __restrict__ Bt,
    const float* __restrict__ bias, void* __restrict__ Cv, void* __restrict__ Cv2,
    int K, int N, int mode) {
  __shared__ __align__(16) short As[64 * 64];   // 8 KB
  __shared__ __align__(16) short Bs[64 * 64];   // 8 KB
  const int t = threadIdx.x;
  const int wave = t >> 6, lane = t & 63;
  const int m0 = blockIdx.y * 64, n0 = blockIdx.x * 64;

  const int srow = t >> 3;                  // 0..31
  const int sw   = (t & 7) ^ (srow & 7);
  const bf16* Ag = A  + (size_t)(m0 + srow) * lda + sw * 8;
  const bf16* Bg = Bt + (size_t)(n0 + srow) * K + sw * 8;

  const int fr = lane & 15, kq = lane >> 4;
  const int wm = (wave >> 1) * 32, wn = (wave & 1) * 32;
  f32x4 acc[2][2] = {};

  for (int k0 = 0; k0 < K; k0 += 64) {
    async_ld16(Ag + k0,                    As + wave * 512);
    async_ld16(Ag + (size_t)32 * lda + k0, As + 2048 + wave * 512);
    async_ld16(Bg + k0,                    Bs + wave * 512);
    async_ld16(Bg + (size_t)32 * K + k0,   Bs + 2048 + wave * 512);
    __syncthreads();
    #pragma unroll
    for (int s = 0; s < 2; s++) {
      short8 a[2], b[2];
      #pragma unroll
      for (int i = 0; i < 2; i++) {
        int r = wm + 16 * i + fr;
        int p = (kq + 4 * s) ^ (r & 7);
        a[i] = *(const short8*)(As + r * 64 + p * 8);
      }
      #pragma unroll
      for (int j = 0; j < 2; j++) {
        int r = wn + 16 * j + fr;
        int p = (kq + 4 * s) ^ (r & 7);
        b[j] = *(const short8*)(Bs + r * 64 + p * 8);
      }
      #pragma unroll
      for (int i = 0; i < 2; i++)
        #pragma unroll
        for (int j = 0; j < 2; j++)
          acc[i][j] = __builtin_amdgcn_mfma_f32_16x16x32_bf16(a[i], b[j], acc[i][j], 0, 0, 0);
    }
    __syncthreads();
  }

  // C/D layout: col = lane&15, row = (lane>>4)*4 + reg
  #pragma unroll
  for (int i = 0; i < 2; i++) {
    #pragma unroll
    for (int j = 0; j < 2; j++) {
      const int r0 = m0 + wm + 16 * i + kq * 4;
      const int c  = n0 + wn + 16 * j + fr;
      const float bv = bias[c];
      if (mode == 4) {
        if (n0 < 768) {
          #pragma unroll
          for (int ri = 0; ri < 4; ri++)
            ((bf16*)Cv)[(size_t)(r0 + ri) * 768 + c] = f2b(acc[i][j][ri] + bv);
        } else {
          __align__(8) bf16 tb[4];
          #pragma unroll
          for (int ri = 0; ri < 4; ri++) tb[ri] = f2b(acc[i][j][ri] + bv);
          *(short4*)((short*)Cv2 + ((size_t)(c - 768) << 11) + r0) = *(short4*)&tb[0];
        }
      } else {
        #pragma unroll
        for (int ri = 0; ri < 4; ri++) {
          float val = acc[i][j][ri] + bv;
          val = 0.5f * val * (1.0f + erff(val * 0.70710678118654752f));
          ((bf16*)Cv)[(size_t)(r0 + ri) * N + c] = f2b(val);
        }
      }
    }
  }
}

// ---------------------------------------------------------------------------
// Residual / split-K GEMM (fp32 out), 64x64 tile, N = 768.
// zsplit==1: x[idx] = acc + bias + x[idx].   grid (12, 32)
// zsplit>1 : part[z*S*E + idx] = acc.        grid (12, 32, zsplit)
// ---------------------------------------------------------------------------
__global__ __launch_bounds__(256) void gemm_resid_kernel(
    const bf16* __restrict__ A, int lda, const bf16* __restrict__ Bt,
    const float* __restrict__ bias, float* __restrict__ x,
    float* __restrict__ part, int K, int zsplit, int Ksplit) {
  __shared__ __align__(16) short As[64 * 64];
  __shared__ __align__(16) short Bs[64 * 64];
  const int t = threadIdx.x;
  const int wave = t >> 6, lane = t & 63;
  const int m0 = blockIdx.y * 64, n0 = blockIdx.x * 64;
  const int z = blockIdx.z;
  const int kBeg = z * Ksplit, kEnd = kBeg + Ksplit;

  const int srow = t >> 3;
  const int sw   = (t & 7) ^ (srow & 7);
  const bf16* Ag = A  + (size_t)(m0 + srow) * lda + sw * 8;
  const bf16* Bg = Bt + (size_t)(n0 + srow) * K + sw * 8;

  const int fr = lane & 15, kq = lane >> 4;
  const int wm = (wave >> 1) * 32, wn = (wave & 1) * 32;
  f32x4 acc[2][2] = {};

  for (int k0 = kBeg; k0 < kEnd; k0 += 64) {
    async_ld16(Ag + k0,                    As + wave * 512);
    async_ld16(Ag + (size_t)32 * lda + k0, As + 2048 + wave * 512);
    async_ld16(Bg + k0,                    Bs + wave * 512);
    async_ld16(Bg + (size_t)32 * K + k0,   Bs + 2048 + wave * 512);
    __syncthreads();
    #pragma unroll
    for (int s = 0; s < 2; s++) {
      short8 a[2], b[2];
      #pragma unroll
      for (int i = 0; i < 2; i++) {
        int r = wm + 16 * i + fr;
        int p = (kq + 4 * s) ^ (r & 7);
        a[i] = *(const short8*)(As + r * 64 + p * 8);
      }
      #pragma unroll
      for (int j = 0; j < 2; j++) {
        int r = wn + 16 * j + fr;
        int p = (kq + 4 * s) ^ (r & 7);
        b[j] = *(const short8*)(Bs + r * 64 + p * 8);
      }
      #pragma unroll
      for (int i = 0; i < 2; i++)
        #pragma unroll
        for (int j = 0; j < 2; j++)
          acc[i][j] = __builtin_amdgcn_mfma_f32_16x16x32_bf16(a[i], b[j], acc[i][j], 0, 0, 0);
    }
    __syncthreads();
  }

  #pragma unroll
  for (int i = 0; i < 2; i++) {
    #pragma unroll
    for (int j = 0; j < 2; j++) {
      const int r0 = m0 + wm + 16 * i + kq * 4;
      const int c  = n0 + wn + 16 * j + fr;
      if (zsplit > 1) {
        #pragma unroll
        for (int ri = 0; ri < 4; ri++)
          part[(size_t)z * SS * EE + (size_t)(r0 + ri) * EE + c] = acc[i][j][ri];
      } else {
        const float bv = bias[c];
        #pragma unroll
        for (int ri = 0; ri < 4; ri++) {
          const size_t idx = (size_t)(r0 + ri) * EE + c;
          x[idx] = acc[i][j][ri] + bv + x[idx];
        }
      }
    }
  }
}

// ---------------------------------------------------------------------------
// Fused attention: M_h = 0.125 * K_h^T V_h (4 waves x 512 s, bf16 LDS
// partials), then Gt[n][h*64+d1] = (M_h @ Wo_h)[d1][n] for a 128-n tile.
// grid (6, 12). LDS 40 KB.
// ---------------------------------------------------------------------------
__global__ __launch_bounds__(256) void attn_fused_kernel(
    const bf16* __restrict__ kvT, const bf16* __restrict__ Wo_t,
    bf16* __restrict__ Gt) {
  __shared__ short pbuf[4][4096];
  __shared__ short Ms[4096];
  const int nt = blockIdx.x, h = blockIdx.y;
  const int lane = threadIdx.x & 63, wave = threadIdx.x >> 6;
  const int fr = lane & 15, kq = lane >> 4;
  const short* kT = (const short*)kvT + (size_t)h * 64 * 2048;
  const short* vT = (const short*)kvT + (size_t)(768 + h * 64) * 2048;

  f32x4 acc[4][4] = {};
  for (int it = 0; it < 8; it++) {
    const int s0 = (it * 4 + wave) * 64;
    #pragma unroll
    for (int s = 0; s < 2; s++) {
      short8 a[4], b[4];
      #pragma unroll
      for (int i = 0; i < 4; i++)
        a[i] = *(const short8*)(kT + (size_t)(16 * i + fr) * 2048 + s0 + s * 32 + kq * 8);
      #pragma unroll
      for (int j = 0; j < 4; j++)
        b[j] = *(const short8*)(vT + (size_t)(16 * j + fr) * 2048 + s0 + s * 32 + kq * 8);
      #pragma unroll
      for (int i = 0; i < 4; i++)
        #pragma unroll
        for (int j = 0; j < 4; j++)
          acc[i][j] = __builtin_amdgcn_mfma_f32_16x16x32_bf16(a[i], b[j], acc[i][j], 0, 0, 0);
    }
  }
  #pragma unroll
  for (int i = 0; i < 4; i++)
    #pragma unroll
    for (int j = 0; j < 4; j++)
      #pragma unroll
      for (int ri = 0; ri < 4; ri++)
        pbuf[wave][(16 * i + kq * 4 + ri) * 64 + 16 * j + fr] =
            (short)__bfloat16_as_ushort(f2b(acc[i][j][ri]));
  __syncthreads();
  {
    int e0 = threadIdx.x * 16;
    #pragma unroll
    for (int e = 0; e < 16; e++) {
      float s = b2f(pbuf[0][e0 + e]) + b2f(pbuf[1][e0 + e]) +
                b2f(pbuf[2][e0 + e]) + b2f(pbuf[3][e0 + e]);
      Ms[e0 + e] = (short)__bfloat16_as_ushort(f2b(s * 0.125f));
    }
  }
  __syncthreads();

  const int nb = nt * 128 + wave * 32;
  f32x4 g[4][2] = {};
  #pragma unroll
  for (int s = 0; s < 2; s++) {
    short8 a[4], b[2];
    #pragma unroll
    for (int i = 0; i < 4; i++)
      a[i] = *(const short8*)(Ms + (16 * i + fr) * 64 + s * 32 + kq * 8);
    #pragma unroll
    for (int j = 0; j < 2; j++)
      b[j] = *(const short8*)((const short*)Wo_t +
             (size_t)(nb + 16 * j + fr) * 768 + h * 64 + s * 32 + kq * 8);
    #pragma unroll
    for (int i = 0; i < 4; i++)
      #pragma unroll
      for (int j = 0; j < 2; j++)
        g[i][j] = __builtin_amdgcn_mfma_f32_16x16x32_bf16(a[i], b[j], g[i][j], 0, 0, 0);
  }
  #pragma unroll
  for (int i = 0; i < 4; i++)
    #pragma unroll
    for (int j = 0; j < 2; j++) {
      const int c = nb + 16 * j + fr;
      const int d1 = 16 * i + kq * 4;
      __align__(8) bf16 tb[4];
      #pragma unroll
      for (int ri = 0; ri < 4; ri++) tb[ri] = f2b(g[i][j][ri]);
      *(short4*)((short*)Gt + (size_t)c * 768 + h * 64 + d1) = *(short4*)&tb[0];
    }
}

// ---------------------------------------------------------------------------
extern "C" void kernel_launch(void* const* d_in, const int* in_sizes, int n_in,
                              void* d_out, int out_size, void* d_ws, size_t ws_size,
                              hipStream_t stream) {
  const float* emb  = (const float*)d_in[0];
  const float* wpe  = (const float*)d_in[1];
  const float* ln1g = (const float*)d_in[2];
  const float* ln1b = (const float*)d_in[3];
  const float* Wq   = (const float*)d_in[4];
  const float* bq   = (const float*)d_in[5];
  const float* Wk   = (const float*)d_in[6];
  const float* bk   = (const float*)d_in[7];
  const float* Wv   = (const float*)d_in[8];
  const float* bv   = (const float*)d_in[9];
  const float* Wo   = (const float*)d_in[10];
  const float* bo   = (const float*)d_in[11];
  const float* ln2g = (const float*)d_in[12];
  const float* ln2b = (const float*)d_in[13];
  const float* W1   = (const float*)d_in[14];
  const float* b1   = (const float*)d_in[15];
  const float* W2   = (const float*)d_in[16];
  const float* b2   = (const float*)d_in[17];
  const float* lnfg = (const float*)d_in[18];
  const float* lnfb = (const float*)d_in[19];

  // Workspace (~103 MB of 256 MiB)
  char* w = (char*)d_ws;
  bf16*  WtAll = (bf16*)w;   w += (size_t)4 * 7077888 * 2;    // 56.6 MB
  float* bqkvA = (float*)w;  w += (size_t)4 * 2304 * 4;
  float* x     = (float*)w;  w += (size_t)SS * EE * 4;        // 6.3 MB
  bf16*  hb    = (bf16*)w;   w += (size_t)SS * EE * 2;        // 3.1 MB
  bf16*  qkvQ  = (bf16*)w;   w += (size_t)SS * EE * 2;        // 3.1 MB
  bf16*  kvT   = (bf16*)w;   w += (size_t)1536 * 2048 * 2;    // 6.3 MB
  bf16*  Gt    = (bf16*)w;   w += (size_t)EE * EE * 2;        // 1.2 MB
  bf16*  mb2   = (bf16*)w;   w += (size_t)SS * FFF * 2;       // 12.6 MB
  float* cpart = (float*)w;  w += (size_t)2 * SS * EE * 4;    // 12.6 MB

  dim3 blk(256);
  transpose_all_kernel<<<13824, blk, 0, stream>>>(Wq, Wk, Wv, Wo, W1, W2, WtAll);
  concat_bias_all_kernel<<<36, blk, 0, stream>>>(bq, bk, bv, bqkvA);

  for (int l = 0; l < LL; l++) {
    bf16* Wl = WtAll + (size_t)l * 7077888;
    bf16* Wqkv_t = Wl;
    bf16* Wo_t   = Wl + 1769472;
    bf16* W1_t   = Wl + 2359296;
    bf16* W2_t   = Wl + 4718592;

    if (l == 0) {
      // x = emb + wpe, LN -> hb
      ln_fused_kernel<bf16><<<SS, blk, 0, stream>>>(
          x, nullptr, emb, 1, wpe, ln1g, ln1b, 1, 0, hb);
    } else {
      // x += b2(prev) + FF2 partials, LN -> hb
      ln_fused_kernel<bf16><<<SS, blk, 0, stream>>>(
          x, b2 + (l - 1) * EE, cpart, 2, nullptr,
          ln1g + l * EE, ln1b + l * EE, 1, 1, hb);
    }
    // fused QKV GEMM: Q -> qkvQ (ld 768), K/V -> kvT transposed. 1152 blocks.
    gemm_bf16_kernel<<<dim3(36, 32), blk, 0, stream>>>(
        hb, EE, Wqkv_t, bqkvA + l * 2304, qkvQ, kvT, EE, 2304, 4);
    // attention folded through Wo: Gt = (M_h @ Wo_h) stacked
    attn_fused_kernel<<<dim3(6, HH), blk, 0, stream>>>(kvT, Wo_t, Gt);
    // x += Q @ Gt^T + bo  (384 blocks, direct residual)
    gemm_resid_kernel<<<dim3(12, 32), blk, 0, stream>>>(
        qkvQ, EE, Gt, bo + l * EE, x, nullptr, EE, 1, EE);
    ln_fused_kernel<bf16><<<SS, blk, 0, stream>>>(
        x, nullptr, nullptr, 0, nullptr, ln2g + l * EE, ln2b + l * EE, 0, 1, hb);
    // FF1 + GELU  (1536 blocks)
    gemm_bf16_kernel<<<dim3(48, 32), blk, 0, stream>>>(
        hb, EE, W1_t, b1 + l * FFF, mb2, nullptr, EE, FFF, 1);
    // FF2 split-K=2 partials (768 blocks of 24 iters); bias+residual in next LN
    gemm_resid_kernel<<<dim3(12, 32, 2), blk, 0, stream>>>(
        mb2, FFF, W2_t, nullptr, nullptr, cpart, FFF, 2, 1536);
  }
  ln_fused_kernel<float><<<SS, blk, 0, stream>>>(
      x, b2 + 3 * EE, cpart, 2, nullptr, lnfg, lnfb, 0, 1, (float*)d_out);
}